// Round 11
// baseline (408.713 us; speedup 1.0000x reference)
//
#include <hip/hip_runtime.h>

typedef unsigned short u16;
typedef unsigned int u32;
typedef __attribute__((ext_vector_type(8))) short bf16x8;
typedef __attribute__((ext_vector_type(4))) float f32x4;

__device__ __forceinline__ float bf(u16 u){ return __uint_as_float(((u32)u) << 16); }
__device__ __forceinline__ float bf_lo(u32 u){ return __uint_as_float(u << 16); }
__device__ __forceinline__ float bf_hi(u32 u){ return __uint_as_float(u & 0xFFFF0000u); }
__device__ __forceinline__ u16 to_bf16(float f){
    u32 x = __float_as_uint(f);
    u32 r = (x + 0x7FFFu + ((x >> 16) & 1u)) >> 16;
    return (u16)r;
}
__device__ __forceinline__ float leaky(float v){ return (v >= 0.f) ? v : 0.2f * v; }
__device__ __forceinline__ float eexp(float v){
    return __expf(fminf(leaky(v), 80.f));
}
__device__ __forceinline__ float ldany(const void* p, int i, int fl){
    return fl ? bf(((const u16*)p)[i]) : ((const float*)p)[i];
}
__device__ __forceinline__ u16 ldany_bf(const void* p, int i, int fl){
    return fl ? ((const u16*)p)[i] : to_bf16(((const float*)p)[i]);
}

constexpr int CB = 2048;   // binned-count blocks in mega1
constexpr int SB = 2048;   // binned-scatter blocks in mega2

// ================= mega1: XCD-binned degree count + all input conversion =================
struct Mega1Args {
    const int* dst; const int* src; int* deg; int E; int binsz;
    const void* xin; u16* Xb; int nx;           // N*128
    const void* W1; const void* W2; u16* W1t; u16* W2t;
    const void* vin[6]; float* vout[6];
    int* flag;
};
__global__ __launch_bounds__(256) void mega1(Mega1Args a){
    int b = blockIdx.x;
    if (b < CB){
        int bin = b & 7, grp = b >> 3, ngrp = CB >> 3;
        int lo = bin * a.binsz;
        for (int i = grp * 256 + threadIdx.x; i < a.E; i += ngrp * 256){
            int d = a.dst[i];
            if ((u32)(d - lo) >= (u32)a.binsz) continue;
            if (a.src[i] != d) atomicAdd(&a.deg[d], 1);
        }
        return;
    }
    // conversion blocks: self-detect dtype from x[0..255] (wave 0), broadcast via LDS
    __shared__ int sflag;
    const u16* x16 = (const u16*)a.xin;
    if (threadIdx.x < 64){
        int ok = 1;
        for (int i = threadIdx.x; i < 256; i += 64){
            u16 v = x16[i];
            int e = (v >> 7) & 0xFF;
            if (!((e >= 100 && e <= 140) || (v & 0x7FFFu) == 0)) ok = 0;
        }
        unsigned long long bl = __ballot(ok);
        if (threadIdx.x == 0) sflag = (__popcll(bl) >= 62) ? 1 : 0;
    }
    __syncthreads();
    int fl = sflag;
    int ci = (b - CB) * 256 + threadIdx.x;
    if (ci == 0) *a.flag = fl;
    if (ci < a.nx){ a.Xb[ci] = ldany_bf(a.xin, ci, fl); return; }
    ci -= a.nx;
    if (ci < 128 * 128){
        int n = ci >> 7, k = ci & 127;
        a.W1t[ci] = ldany_bf(a.W1, k * 128 + n, fl);
        return;
    }
    ci -= 128 * 128;
    if (ci < 64 * 128){
        int n = ci >> 7, k = ci & 127;
        a.W2t[ci] = ldany_bf(a.W2, k * 64 + n, fl);
        return;
    }
    ci -= 64 * 128;
    const int vsz[6] = {128, 128, 128, 64, 64, 64};
    #pragma unroll
    for (int s = 0; s < 6; s++){
        if (ci < vsz[s]){ a.vout[s][ci] = ldany(a.vin[s], ci, fl); return; }
        ci -= vsz[s];
    }
}

// ================= single-block exclusive scan (replaces 3 scan dispatches) =================
__global__ __launch_bounds__(1024) void scan_full(const int* __restrict__ deg,
                                                  int* __restrict__ off,
                                                  int* __restrict__ cur, int N){
    __shared__ int wsum[16];
    int t = threadIdx.x;
    int chunk = (N + 1023) / 1024;
    int base = t * chunk;
    int s = 0;
    for (int i = 0; i < chunk; i++){ int idx = base + i; if (idx < N) s += deg[idx]; }
    int v = s;
    #pragma unroll
    for (int d = 1; d < 64; d <<= 1){
        int o = __shfl_up(v, d);
        if ((t & 63) >= d) v += o;
    }
    if ((t & 63) == 63) wsum[t >> 6] = v;
    __syncthreads();
    int woff = 0;
    for (int wv = 0; wv < (t >> 6); wv++) woff += wsum[wv];
    int run = woff + v - s;       // exclusive prefix
    for (int i = 0; i < chunk; i++){
        int idx = base + i;
        if (idx < N){
            int dv = deg[idx];
            off[idx] = run; cur[idx] = run;
            run += dv;
        }
    }
    if (t == 1023) off[N] = run;
}

// ====== mega2: XCD-binned scatter + MFMA GEMM1 (128 cols) with fused attention logits ======
struct Mega2Args {
    const int* dst; const int* src; int* cur; u16* csr; int E; int binsz;
    const u16* Xb; const u16* W1t; u16* HB;
    const float* a_s; const float* a_d; float* al_s; float* al_d;
    int N;
};
__global__ __launch_bounds__(256) void mega2(Mega2Args a){
    int b = blockIdx.x;
    if (b < SB){
        int bin = b & 7, grp = b >> 3, ngrp = SB >> 3;
        int lo = bin * a.binsz;
        for (int i = grp * 256 + threadIdx.x; i < a.E; i += ngrp * 256){
            int d = a.dst[i];
            if ((u32)(d - lo) >= (u32)a.binsz) continue;
            int s = a.src[i];
            if (s != d){
                int pos = atomicAdd(&a.cur[d], 1);
                a.csr[pos] = (u16)s;
            }
        }
        return;
    }
    int gb = b - SB;
    int lane = threadIdx.x & 63;
    int w = threadIdx.x >> 6;
    int row0 = gb * 64 + w * 16;
    int m = lane & 15, quad = lane >> 4;
    int arow = row0 + m;
    if (arow >= a.N) arow = a.N - 1;
    f32x4 acc[8];
    #pragma unroll
    for (int j = 0; j < 8; j++) acc[j] = (f32x4){0.f, 0.f, 0.f, 0.f};
    const u16* ap = a.Xb + (size_t)arow * 128 + quad * 8;
    const u16* bp = a.W1t + (size_t)m * 128 + quad * 8;
    #pragma unroll
    for (int kc = 0; kc < 4; kc++){
        bf16x8 av = *(const bf16x8*)(ap + kc * 32);
        #pragma unroll
        for (int nb = 0; nb < 8; nb++){
            bf16x8 bv = *(const bf16x8*)(bp + nb * 16 * 128 + kc * 32);
            acc[nb] = __builtin_amdgcn_mfma_f32_16x16x32_bf16(av, bv, acc[nb], 0, 0, 0);
        }
    }
    #pragma unroll
    for (int nb = 0; nb < 8; nb++){
        #pragma unroll
        for (int r = 0; r < 4; r++){
            int grow = row0 + quad * 4 + r;
            if (grow < a.N) a.HB[(size_t)grow * 128 + nb * 16 + m] = to_bf16(acc[nb][r]);
        }
    }
    // fused logits: col = nb*16+m, a_s flat [h*32+f] == col index
    float asr[8], adr[8];
    #pragma unroll
    for (int nb = 0; nb < 8; nb++){ asr[nb] = a.a_s[nb * 16 + m]; adr[nb] = a.a_d[nb * 16 + m]; }
    #pragma unroll
    for (int r = 0; r < 4; r++){
        int grow = row0 + quad * 4 + r;
        #pragma unroll
        for (int h = 0; h < 4; h++){
            float ps = acc[2 * h][r] * asr[2 * h] + acc[2 * h + 1][r] * asr[2 * h + 1];
            float pd = acc[2 * h][r] * adr[2 * h] + acc[2 * h + 1][r] * adr[2 * h + 1];
            #pragma unroll
            for (int d = 1; d < 16; d <<= 1){
                ps += __shfl_xor(ps, d);
                pd += __shfl_xor(pd, d);
            }
            if (m == h && grow < a.N){
                a.al_s[grow * 4 + h] = ps;
                a.al_d[grow * 4 + h] = pd;
            }
        }
    }
}

// ============ GEMM2 (64 cols) with fused logits (H=1) ============
__global__ __launch_bounds__(256) void gemm2_logits(const u16* __restrict__ Xb,
                                                    const u16* __restrict__ Wt,
                                                    u16* __restrict__ HB,
                                                    const float* __restrict__ a_s,
                                                    const float* __restrict__ a_d,
                                                    float* __restrict__ al_s,
                                                    float* __restrict__ al_d, int N){
    int lane = threadIdx.x & 63;
    int w = threadIdx.x >> 6;
    int row0 = blockIdx.x * 64 + w * 16;
    int m = lane & 15, quad = lane >> 4;
    int arow = row0 + m;
    if (arow >= N) arow = N - 1;
    f32x4 acc[4];
    #pragma unroll
    for (int j = 0; j < 4; j++) acc[j] = (f32x4){0.f, 0.f, 0.f, 0.f};
    const u16* ap = Xb + (size_t)arow * 128 + quad * 8;
    const u16* bp = Wt + (size_t)m * 128 + quad * 8;
    #pragma unroll
    for (int kc = 0; kc < 4; kc++){
        bf16x8 av = *(const bf16x8*)(ap + kc * 32);
        #pragma unroll
        for (int nb = 0; nb < 4; nb++){
            bf16x8 bv = *(const bf16x8*)(bp + nb * 16 * 128 + kc * 32);
            acc[nb] = __builtin_amdgcn_mfma_f32_16x16x32_bf16(av, bv, acc[nb], 0, 0, 0);
        }
    }
    #pragma unroll
    for (int nb = 0; nb < 4; nb++){
        #pragma unroll
        for (int r = 0; r < 4; r++){
            int grow = row0 + quad * 4 + r;
            if (grow < N) HB[(size_t)grow * 64 + nb * 16 + m] = to_bf16(acc[nb][r]);
        }
    }
    float asr[4], adr[4];
    #pragma unroll
    for (int nb = 0; nb < 4; nb++){ asr[nb] = a_s[nb * 16 + m]; adr[nb] = a_d[nb * 16 + m]; }
    #pragma unroll
    for (int r = 0; r < 4; r++){
        int grow = row0 + quad * 4 + r;
        float ps = 0.f, pd = 0.f;
        #pragma unroll
        for (int nb = 0; nb < 4; nb++){ ps += acc[nb][r] * asr[nb]; pd += acc[nb][r] * adr[nb]; }
        #pragma unroll
        for (int d = 1; d < 16; d <<= 1){
            ps += __shfl_xor(ps, d);
            pd += __shfl_xor(pd, d);
        }
        if (m == 0 && grow < N){
            al_s[grow] = ps;
            al_d[grow] = pd;
        }
    }
}

// ------- layer-1 aggregate (unchanged from round 10) -------
__global__ __launch_bounds__(256) void gat_agg1(const int* __restrict__ off,
                                                const u16* __restrict__ csr,
                                                float* __restrict__ eex,
                                                const u16* __restrict__ h1,
                                                const float* __restrict__ als,
                                                const float* __restrict__ ald,
                                                const float* __restrict__ b1,
                                                u16* __restrict__ outm, int N){
    int lane = threadIdx.x & 63;
    int n = blockIdx.x * 4 + (threadIdx.x >> 6);
    if (n >= N) return;
    int o0 = off[n], o1 = off[n + 1];
    int h = lane & 3;
    float aldh = ald[n * 4 + h];
    float s = 0.f;
    for (int j = o0 + (lane >> 2); j < o1; j += 16){
        int sc = csr[j];
        float e = eexp(als[sc * 4 + h] + aldh);
        eex[j * 4 + h] = e;
        s += e;
    }
    #pragma unroll
    for (int d = 4; d < 64; d <<= 1) s += __shfl_xor(s, d);
    float esx = eexp(als[n * 4 + h] + aldh);
    float inv = 1.f / (s + esx + 1e-16f);
    float psv = esx * inv;
    __builtin_amdgcn_s_waitcnt(0);
    int q = lane >> 4, ql = lane & 15;
    int c0 = ql * 8;
    int head = ql >> 2;
    float invh = __shfl(inv, head);
    float ps   = __shfl(psv, head);
    float acc[8] = {};
    int j = o0 + q;
    for (; j + 4 < o1; j += 8){
        int sc0 = csr[j], sc1 = csr[j + 4];
        float p0 = eex[j * 4 + head] * invh;
        float p1 = eex[(j + 4) * 4 + head] * invh;
        uint4 u0 = *(const uint4*)&h1[(size_t)sc0 * 128 + c0];
        uint4 u1 = *(const uint4*)&h1[(size_t)sc1 * 128 + c0];
        acc[0] += p0 * bf_lo(u0.x) + p1 * bf_lo(u1.x);
        acc[1] += p0 * bf_hi(u0.x) + p1 * bf_hi(u1.x);
        acc[2] += p0 * bf_lo(u0.y) + p1 * bf_lo(u1.y);
        acc[3] += p0 * bf_hi(u0.y) + p1 * bf_hi(u1.y);
        acc[4] += p0 * bf_lo(u0.z) + p1 * bf_lo(u1.z);
        acc[5] += p0 * bf_hi(u0.z) + p1 * bf_hi(u1.z);
        acc[6] += p0 * bf_lo(u0.w) + p1 * bf_lo(u1.w);
        acc[7] += p0 * bf_hi(u0.w) + p1 * bf_hi(u1.w);
    }
    if (j < o1){
        int sc = csr[j];
        float p = eex[j * 4 + head] * invh;
        uint4 u = *(const uint4*)&h1[(size_t)sc * 128 + c0];
        acc[0] += p * bf_lo(u.x); acc[1] += p * bf_hi(u.x);
        acc[2] += p * bf_lo(u.y); acc[3] += p * bf_hi(u.y);
        acc[4] += p * bf_lo(u.z); acc[5] += p * bf_hi(u.z);
        acc[6] += p * bf_lo(u.w); acc[7] += p * bf_hi(u.w);
    }
    if (q == 0){
        uint4 u = *(const uint4*)&h1[(size_t)n * 128 + c0];
        acc[0] += ps * bf_lo(u.x); acc[1] += ps * bf_hi(u.x);
        acc[2] += ps * bf_lo(u.y); acc[3] += ps * bf_hi(u.y);
        acc[4] += ps * bf_lo(u.z); acc[5] += ps * bf_hi(u.z);
        acc[6] += ps * bf_lo(u.w); acc[7] += ps * bf_hi(u.w);
    }
    #pragma unroll
    for (int i = 0; i < 8; i++){
        acc[i] += __shfl_xor(acc[i], 16);
        acc[i] += __shfl_xor(acc[i], 32);
    }
    if (q == 0){
        float4 bA = *(const float4*)&b1[c0];
        float4 bB = *(const float4*)&b1[c0 + 4];
        u16 pk[8];
        pk[0] = to_bf16(fmaxf(acc[0] + bA.x, 0.f));
        pk[1] = to_bf16(fmaxf(acc[1] + bA.y, 0.f));
        pk[2] = to_bf16(fmaxf(acc[2] + bA.z, 0.f));
        pk[3] = to_bf16(fmaxf(acc[3] + bA.w, 0.f));
        pk[4] = to_bf16(fmaxf(acc[4] + bB.x, 0.f));
        pk[5] = to_bf16(fmaxf(acc[5] + bB.y, 0.f));
        pk[6] = to_bf16(fmaxf(acc[6] + bB.z, 0.f));
        pk[7] = to_bf16(fmaxf(acc[7] + bB.w, 0.f));
        *(uint4*)&outm[(size_t)n * 128 + c0] = *(uint4*)pk;
    }
}

// ------- layer-2 aggregate (unchanged from round 10) -------
__global__ __launch_bounds__(256) void gat_agg2(const int* __restrict__ off,
                                                const u16* __restrict__ csr,
                                                float* __restrict__ eex,
                                                const u16* __restrict__ h2,
                                                const float* __restrict__ als,
                                                const float* __restrict__ ald,
                                                const float* __restrict__ b2,
                                                void* __restrict__ outv, int N,
                                                const int* __restrict__ flag){
    int lane = threadIdx.x & 63;
    int n = blockIdx.x * 4 + (threadIdx.x >> 6);
    if (n >= N) return;
    int o0 = off[n], o1 = off[n + 1];
    float aldn = ald[n];
    float s = 0.f;
    for (int j = o0 + lane; j < o1; j += 64){
        int sc = csr[j];
        float e = eexp(als[sc] + aldn);
        eex[j] = e;
        s += e;
    }
    #pragma unroll
    for (int d = 1; d < 64; d <<= 1) s += __shfl_xor(s, d);
    float esx = eexp(als[n] + aldn);
    float inv = 1.f / (s + esx + 1e-16f);
    float ps = esx * inv;
    __builtin_amdgcn_s_waitcnt(0);
    int oc = lane >> 3, ol = lane & 7;
    int c0 = ol * 8;
    float acc[8] = {};
    int j = o0 + oc;
    for (; j + 8 < o1; j += 16){
        int sc0 = csr[j], sc1 = csr[j + 8];
        float p0 = eex[j] * inv;
        float p1 = eex[j + 8] * inv;
        uint4 u0 = *(const uint4*)&h2[(size_t)sc0 * 64 + c0];
        uint4 u1 = *(const uint4*)&h2[(size_t)sc1 * 64 + c0];
        acc[0] += p0 * bf_lo(u0.x) + p1 * bf_lo(u1.x);
        acc[1] += p0 * bf_hi(u0.x) + p1 * bf_hi(u1.x);
        acc[2] += p0 * bf_lo(u0.y) + p1 * bf_lo(u1.y);
        acc[3] += p0 * bf_hi(u0.y) + p1 * bf_hi(u1.y);
        acc[4] += p0 * bf_lo(u0.z) + p1 * bf_lo(u1.z);
        acc[5] += p0 * bf_hi(u0.z) + p1 * bf_hi(u1.z);
        acc[6] += p0 * bf_lo(u0.w) + p1 * bf_lo(u1.w);
        acc[7] += p0 * bf_hi(u0.w) + p1 * bf_hi(u1.w);
    }
    if (j < o1){
        int sc = csr[j];
        float p = eex[j] * inv;
        uint4 u = *(const uint4*)&h2[(size_t)sc * 64 + c0];
        acc[0] += p * bf_lo(u.x); acc[1] += p * bf_hi(u.x);
        acc[2] += p * bf_lo(u.y); acc[3] += p * bf_hi(u.y);
        acc[4] += p * bf_lo(u.z); acc[5] += p * bf_hi(u.z);
        acc[6] += p * bf_lo(u.w); acc[7] += p * bf_hi(u.w);
    }
    if (oc == 0){
        uint4 u = *(const uint4*)&h2[(size_t)n * 64 + c0];
        acc[0] += ps * bf_lo(u.x); acc[1] += ps * bf_hi(u.x);
        acc[2] += ps * bf_lo(u.y); acc[3] += ps * bf_hi(u.y);
        acc[4] += ps * bf_lo(u.z); acc[5] += ps * bf_hi(u.z);
        acc[6] += ps * bf_lo(u.w); acc[7] += ps * bf_hi(u.w);
    }
    #pragma unroll
    for (int i = 0; i < 8; i++){
        acc[i] += __shfl_xor(acc[i], 8);
        acc[i] += __shfl_xor(acc[i], 16);
        acc[i] += __shfl_xor(acc[i], 32);
    }
    if (oc == 0){
        float4 bA = *(const float4*)&b2[c0];
        float4 bB = *(const float4*)&b2[c0 + 4];
        float r[8];
        r[0] = acc[0] + bA.x; r[1] = acc[1] + bA.y;
        r[2] = acc[2] + bA.z; r[3] = acc[3] + bA.w;
        r[4] = acc[4] + bB.x; r[5] = acc[5] + bB.y;
        r[6] = acc[6] + bB.z; r[7] = acc[7] + bB.w;
        if (*flag){
            u16 pk[8];
            #pragma unroll
            for (int i = 0; i < 8; i++) pk[i] = to_bf16(r[i]);
            *(uint4*)&((u16*)outv)[(size_t)n * 64 + c0] = *(uint4*)pk;
        } else {
            float* op = &((float*)outv)[(size_t)n * 64 + c0];
            *(float4*)op = make_float4(r[0], r[1], r[2], r[3]);
            *(float4*)(op + 4) = make_float4(r[4], r[5], r[6], r[7]);
        }
    }
}

extern "C" void kernel_launch(void* const* d_in, const int* in_sizes, int n_in,
                              void* d_out, int out_size, void* d_ws, size_t ws_size,
                              hipStream_t stream){
    const int* ei  = (const int*)d_in[1];
    const int N = in_sizes[0] / 128;
    const int E = in_sizes[1] / 2;
    const int* src = ei;
    const int* dst = ei + E;
    const int binsz = (N + 7) / 8;

    char* w = (char*)d_ws;
    auto alloc = [&](size_t bytes){ char* p = w; w += (bytes + 255) & ~(size_t)255; return p; };
    int*   flag = (int*)  alloc(4);
    int*   deg  = (int*)  alloc((size_t)N * 4);
    int*   off  = (int*)  alloc((size_t)(N + 1) * 4);
    int*   cur  = (int*)  alloc((size_t)N * 4);
    u16*   csr  = (u16*)  alloc((size_t)E * 2);
    float* eex1 = (float*)alloc((size_t)E * 4 * 4);
    u16*   W1t  = (u16*)  alloc(128 * 128 * 2);
    u16*   W2t  = (u16*)  alloc(64 * 128 * 2);
    float* as1f = (float*)alloc(128 * 4);
    float* ad1f = (float*)alloc(128 * 4);
    float* b1f  = (float*)alloc(128 * 4);
    float* as2f = (float*)alloc(64 * 4);
    float* ad2f = (float*)alloc(64 * 4);
    float* b2f  = (float*)alloc(64 * 4);
    u16*   Xb   = (u16*)  alloc((size_t)N * 128 * 2);
    u16*   h1b  = (u16*)  alloc((size_t)N * 128 * 2);
    u16*   hmidb= (u16*)  alloc((size_t)N * 128 * 2);
    u16*   h2b  = (u16*)  alloc((size_t)N * 64 * 2);
    float* als1 = (float*)alloc((size_t)N * 4 * 4);
    float* ald1 = (float*)alloc((size_t)N * 4 * 4);
    float* eex2 = eex1;
    float* als2 = als1;
    float* ald2 = ald1;

    hipMemsetAsync(deg, 0, (size_t)N * 4, stream);

    Mega1Args m1;
    m1.dst = dst; m1.src = src; m1.deg = deg; m1.E = E; m1.binsz = binsz;
    m1.xin = d_in[0]; m1.Xb = Xb; m1.nx = N * 128;
    m1.W1 = d_in[2]; m1.W2 = d_in[6]; m1.W1t = W1t; m1.W2t = W2t;
    const void* vin[6]  = {d_in[3], d_in[4], d_in[5], d_in[7], d_in[8], d_in[9]};
    float* vout[6] = {as1f, ad1f, b1f, as2f, ad2f, b2f};
    for (int s = 0; s < 6; s++){ m1.vin[s] = vin[s]; m1.vout[s] = vout[s]; }
    m1.flag = flag;
    int cvt_total = N * 128 + 128 * 128 + 64 * 128 + 576;
    int m1_blocks = CB + (cvt_total + 255) / 256;
    mega1<<<m1_blocks, 256, 0, stream>>>(m1);

    scan_full<<<1, 1024, 0, stream>>>(deg, off, cur, N);

    Mega2Args m2;
    m2.dst = dst; m2.src = src; m2.cur = cur; m2.csr = csr; m2.E = E; m2.binsz = binsz;
    m2.Xb = Xb; m2.W1t = W1t; m2.HB = h1b;
    m2.a_s = as1f; m2.a_d = ad1f; m2.al_s = als1; m2.al_d = ald1;
    m2.N = N;
    int m2_blocks = SB + (N + 63) / 64;
    mega2<<<m2_blocks, 256, 0, stream>>>(m2);

    gat_agg1<<<(N + 3) / 4, 256, 0, stream>>>(off, csr, eex1, h1b, als1, ald1, b1f, hmidb, N);

    gemm2_logits<<<(N + 63) / 64, 256, 0, stream>>>(hmidb, W2t, h2b, as2f, ad2f, als2, ald2, N);

    gat_agg2<<<(N + 3) / 4, 256, 0, stream>>>(off, csr, eex2, h2b, als2, ald2, b2f, d_out, N, flag);
}

// Round 12
// 302.203 us; speedup vs baseline: 1.3524x; 1.3524x over previous
//
#include <hip/hip_runtime.h>

typedef unsigned short u16;
typedef unsigned int u32;
typedef __attribute__((ext_vector_type(8))) short bf16x8;
typedef __attribute__((ext_vector_type(4))) float f32x4;

__device__ __forceinline__ float bf(u16 u){ return __uint_as_float(((u32)u) << 16); }
__device__ __forceinline__ float bf_lo(u32 u){ return __uint_as_float(u << 16); }
__device__ __forceinline__ float bf_hi(u32 u){ return __uint_as_float(u & 0xFFFF0000u); }
__device__ __forceinline__ u16 to_bf16(float f){
    u32 x = __float_as_uint(f);
    u32 r = (x + 0x7FFFu + ((x >> 16) & 1u)) >> 16;
    return (u16)r;
}
__device__ __forceinline__ float leaky(float v){ return (v >= 0.f) ? v : 0.2f * v; }
__device__ __forceinline__ float eexp(float v){
    return __expf(fminf(leaky(v), 80.f));
}
__device__ __forceinline__ float ldany(const void* p, int i, int fl){
    return fl ? bf(((const u16*)p)[i]) : ((const float*)p)[i];
}
__device__ __forceinline__ u16 ldany_bf(const void* p, int i, int fl){
    return fl ? ((const u16*)p)[i] : to_bf16(((const float*)p)[i]);
}

constexpr int CB = 2048;   // binned-count blocks in mega1
constexpr int SB = 2048;   // binned-scatter blocks in mega2

// ================= mega1: XCD-binned degree count + all input conversion =================
struct Mega1Args {
    const int* dst; const int* src; int* deg; int E; int binsz;
    const void* xin; u16* Xb; int nx;           // N*128
    const void* W1; const void* W2; u16* W1t; u16* W2t;
    const void* vin[6]; float* vout[6];
    int* flag;
};
__global__ __launch_bounds__(256) void mega1(Mega1Args a){
    int b = blockIdx.x;
    if (b < CB){
        int bin = b & 7, grp = b >> 3, ngrp = CB >> 3;
        int lo = bin * a.binsz;
        for (int i = grp * 256 + threadIdx.x; i < a.E; i += ngrp * 256){
            int d = a.dst[i];
            if ((u32)(d - lo) >= (u32)a.binsz) continue;
            if (a.src[i] != d) atomicAdd(&a.deg[d], 1);
        }
        return;
    }
    __shared__ int sflag;
    const u16* x16 = (const u16*)a.xin;
    if (threadIdx.x < 64){
        int ok = 1;
        for (int i = threadIdx.x; i < 256; i += 64){
            u16 v = x16[i];
            int e = (v >> 7) & 0xFF;
            if (!((e >= 100 && e <= 140) || (v & 0x7FFFu) == 0)) ok = 0;
        }
        unsigned long long bl = __ballot(ok);
        if (threadIdx.x == 0) sflag = (__popcll(bl) >= 62) ? 1 : 0;
    }
    __syncthreads();
    int fl = sflag;
    int ci = (b - CB) * 256 + threadIdx.x;
    if (ci == 0) *a.flag = fl;
    if (ci < a.nx){ a.Xb[ci] = ldany_bf(a.xin, ci, fl); return; }
    ci -= a.nx;
    if (ci < 128 * 128){
        int n = ci >> 7, k = ci & 127;
        a.W1t[ci] = ldany_bf(a.W1, k * 128 + n, fl);
        return;
    }
    ci -= 128 * 128;
    if (ci < 64 * 128){
        int n = ci >> 7, k = ci & 127;
        a.W2t[ci] = ldany_bf(a.W2, k * 64 + n, fl);
        return;
    }
    ci -= 64 * 128;
    const int vsz[6] = {128, 128, 128, 64, 64, 64};
    #pragma unroll
    for (int s = 0; s < 6; s++){
        if (ci < vsz[s]){ a.vout[s][ci] = ldany(a.vin[s], ci, fl); return; }
        ci -= vsz[s];
    }
}

// -------- device-wide exclusive scan: 3 coalesced kernels (round-10 proven) --------
constexpr int SCHUNK = 2048;

__global__ __launch_bounds__(256) void scan_part(const int* __restrict__ deg,
                                                 int* __restrict__ bsum, int N){
    __shared__ int red[256];
    int base = blockIdx.x * SCHUNK;
    int t = threadIdx.x;
    int s = 0;
    #pragma unroll
    for (int i = 0; i < SCHUNK / 256; i++){
        int idx = base + i * 256 + t;
        if (idx < N) s += deg[idx];
    }
    red[t] = s;
    __syncthreads();
    for (int d = 128; d > 0; d >>= 1){
        if (t < d) red[t] += red[t + d];
        __syncthreads();
    }
    if (t == 0) bsum[blockIdx.x] = red[0];
}

__global__ void scan_tops(int* __restrict__ bsum, int B){
    int t = threadIdx.x;
    int v = (t < B) ? bsum[t] : 0;
    #pragma unroll
    for (int d = 1; d < 64; d <<= 1){
        int o = __shfl_up(v, d);
        if (t >= d) v += o;
    }
    int ex = __shfl_up(v, 1);
    if (t == 0) ex = 0;
    if (t < B) bsum[t] = ex;
}

__global__ __launch_bounds__(256) void scan_final(const int* __restrict__ deg,
                                                  const int* __restrict__ bsum,
                                                  int* __restrict__ off,
                                                  int* __restrict__ cur, int N){
    __shared__ int lds[SCHUNK];
    __shared__ int wtot[4];
    int base = blockIdx.x * SCHUNK;
    int t = threadIdx.x;
    #pragma unroll
    for (int i = 0; i < SCHUNK / 256; i++){
        int idx = base + i * 256 + t;
        lds[i * 256 + t] = (idx < N) ? deg[idx] : 0;
    }
    __syncthreads();
    int b = t * 8;
    int run = 0;
    int loc[8];
    #pragma unroll
    for (int i = 0; i < 8; i++){ run += lds[b + i]; loc[i] = run; }
    int v = run;
    #pragma unroll
    for (int d = 1; d < 64; d <<= 1){
        int o = __shfl_up(v, d);
        if ((t & 63) >= d) v += o;
    }
    if ((t & 63) == 63) wtot[t >> 6] = v;
    __syncthreads();
    int woff = 0;
    for (int wv = 0; wv < (t >> 6); wv++) woff += wtot[wv];
    int gbase = bsum[blockIdx.x] + woff + v - run;
    #pragma unroll
    for (int i = 0; i < 8; i++){
        int idx = base + b + i;
        if (idx < N){
            int o = gbase + loc[i] - lds[b + i];
            off[idx] = o;
            cur[idx] = o;
            if (idx == N - 1) off[N] = gbase + loc[i];
        }
    }
}

// ====== mega2: XCD-binned scatter + MFMA GEMM1 (128 cols) with fused attention logits ======
struct Mega2Args {
    const int* dst; const int* src; int* cur; u16* csr; int E; int binsz;
    const u16* Xb; const u16* W1t; u16* HB;
    const float* a_s; const float* a_d; float* al_s; float* al_d;
    int N;
};
__global__ __launch_bounds__(256) void mega2(Mega2Args a){
    int b = blockIdx.x;
    if (b < SB){
        int bin = b & 7, grp = b >> 3, ngrp = SB >> 3;
        int lo = bin * a.binsz;
        for (int i = grp * 256 + threadIdx.x; i < a.E; i += ngrp * 256){
            int d = a.dst[i];
            if ((u32)(d - lo) >= (u32)a.binsz) continue;
            int s = a.src[i];
            if (s != d){
                int pos = atomicAdd(&a.cur[d], 1);
                a.csr[pos] = (u16)s;
            }
        }
        return;
    }
    int gb = b - SB;
    int lane = threadIdx.x & 63;
    int w = threadIdx.x >> 6;
    int row0 = gb * 64 + w * 16;
    int m = lane & 15, quad = lane >> 4;
    int arow = row0 + m;
    if (arow >= a.N) arow = a.N - 1;
    f32x4 acc[8];
    #pragma unroll
    for (int j = 0; j < 8; j++) acc[j] = (f32x4){0.f, 0.f, 0.f, 0.f};
    const u16* ap = a.Xb + (size_t)arow * 128 + quad * 8;
    const u16* bp = a.W1t + (size_t)m * 128 + quad * 8;
    #pragma unroll
    for (int kc = 0; kc < 4; kc++){
        bf16x8 av = *(const bf16x8*)(ap + kc * 32);
        #pragma unroll
        for (int nb = 0; nb < 8; nb++){
            bf16x8 bv = *(const bf16x8*)(bp + nb * 16 * 128 + kc * 32);
            acc[nb] = __builtin_amdgcn_mfma_f32_16x16x32_bf16(av, bv, acc[nb], 0, 0, 0);
        }
    }
    #pragma unroll
    for (int nb = 0; nb < 8; nb++){
        #pragma unroll
        for (int r = 0; r < 4; r++){
            int grow = row0 + quad * 4 + r;
            if (grow < a.N) a.HB[(size_t)grow * 128 + nb * 16 + m] = to_bf16(acc[nb][r]);
        }
    }
    float asr[8], adr[8];
    #pragma unroll
    for (int nb = 0; nb < 8; nb++){ asr[nb] = a.a_s[nb * 16 + m]; adr[nb] = a.a_d[nb * 16 + m]; }
    #pragma unroll
    for (int r = 0; r < 4; r++){
        int grow = row0 + quad * 4 + r;
        #pragma unroll
        for (int h = 0; h < 4; h++){
            float ps = acc[2 * h][r] * asr[2 * h] + acc[2 * h + 1][r] * asr[2 * h + 1];
            float pd = acc[2 * h][r] * adr[2 * h] + acc[2 * h + 1][r] * adr[2 * h + 1];
            #pragma unroll
            for (int d = 1; d < 16; d <<= 1){
                ps += __shfl_xor(ps, d);
                pd += __shfl_xor(pd, d);
            }
            if (m == h && grow < a.N){
                a.al_s[grow * 4 + h] = ps;
                a.al_d[grow * 4 + h] = pd;
            }
        }
    }
}

// ============ GEMM2 (64 cols) with fused logits (H=1) ============
__global__ __launch_bounds__(256) void gemm2_logits(const u16* __restrict__ Xb,
                                                    const u16* __restrict__ Wt,
                                                    u16* __restrict__ HB,
                                                    const float* __restrict__ a_s,
                                                    const float* __restrict__ a_d,
                                                    float* __restrict__ al_s,
                                                    float* __restrict__ al_d, int N){
    int lane = threadIdx.x & 63;
    int w = threadIdx.x >> 6;
    int row0 = blockIdx.x * 64 + w * 16;
    int m = lane & 15, quad = lane >> 4;
    int arow = row0 + m;
    if (arow >= N) arow = N - 1;
    f32x4 acc[4];
    #pragma unroll
    for (int j = 0; j < 4; j++) acc[j] = (f32x4){0.f, 0.f, 0.f, 0.f};
    const u16* ap = Xb + (size_t)arow * 128 + quad * 8;
    const u16* bp = Wt + (size_t)m * 128 + quad * 8;
    #pragma unroll
    for (int kc = 0; kc < 4; kc++){
        bf16x8 av = *(const bf16x8*)(ap + kc * 32);
        #pragma unroll
        for (int nb = 0; nb < 4; nb++){
            bf16x8 bv = *(const bf16x8*)(bp + nb * 16 * 128 + kc * 32);
            acc[nb] = __builtin_amdgcn_mfma_f32_16x16x32_bf16(av, bv, acc[nb], 0, 0, 0);
        }
    }
    #pragma unroll
    for (int nb = 0; nb < 4; nb++){
        #pragma unroll
        for (int r = 0; r < 4; r++){
            int grow = row0 + quad * 4 + r;
            if (grow < N) HB[(size_t)grow * 64 + nb * 16 + m] = to_bf16(acc[nb][r]);
        }
    }
    float asr[4], adr[4];
    #pragma unroll
    for (int nb = 0; nb < 4; nb++){ asr[nb] = a_s[nb * 16 + m]; adr[nb] = a_d[nb * 16 + m]; }
    #pragma unroll
    for (int r = 0; r < 4; r++){
        int grow = row0 + quad * 4 + r;
        float ps = 0.f, pd = 0.f;
        #pragma unroll
        for (int nb = 0; nb < 4; nb++){ ps += acc[nb][r] * asr[nb]; pd += acc[nb][r] * adr[nb]; }
        #pragma unroll
        for (int d = 1; d < 16; d <<= 1){
            ps += __shfl_xor(ps, d);
            pd += __shfl_xor(pd, d);
        }
        if (m == 0 && grow < N){
            al_s[grow] = ps;
            al_d[grow] = pd;
        }
    }
}

// ------- layer-1 aggregate -------
__global__ __launch_bounds__(256) void gat_agg1(const int* __restrict__ off,
                                                const u16* __restrict__ csr,
                                                float* __restrict__ eex,
                                                const u16* __restrict__ h1,
                                                const float* __restrict__ als,
                                                const float* __restrict__ ald,
                                                const float* __restrict__ b1,
                                                u16* __restrict__ outm, int N){
    int lane = threadIdx.x & 63;
    int n = blockIdx.x * 4 + (threadIdx.x >> 6);
    if (n >= N) return;
    int o0 = off[n], o1 = off[n + 1];
    int h = lane & 3;
    float aldh = ald[n * 4 + h];
    float s = 0.f;
    for (int j = o0 + (lane >> 2); j < o1; j += 16){
        int sc = csr[j];
        float e = eexp(als[sc * 4 + h] + aldh);
        eex[j * 4 + h] = e;
        s += e;
    }
    #pragma unroll
    for (int d = 4; d < 64; d <<= 1) s += __shfl_xor(s, d);
    float esx = eexp(als[n * 4 + h] + aldh);
    float inv = 1.f / (s + esx + 1e-16f);
    float psv = esx * inv;
    __builtin_amdgcn_s_waitcnt(0);
    int q = lane >> 4, ql = lane & 15;
    int c0 = ql * 8;
    int head = ql >> 2;
    float invh = __shfl(inv, head);
    float ps   = __shfl(psv, head);
    float acc[8] = {};
    int j = o0 + q;
    for (; j + 4 < o1; j += 8){
        int sc0 = csr[j], sc1 = csr[j + 4];
        float p0 = eex[j * 4 + head] * invh;
        float p1 = eex[(j + 4) * 4 + head] * invh;
        uint4 u0 = *(const uint4*)&h1[(size_t)sc0 * 128 + c0];
        uint4 u1 = *(const uint4*)&h1[(size_t)sc1 * 128 + c0];
        acc[0] += p0 * bf_lo(u0.x) + p1 * bf_lo(u1.x);
        acc[1] += p0 * bf_hi(u0.x) + p1 * bf_hi(u1.x);
        acc[2] += p0 * bf_lo(u0.y) + p1 * bf_lo(u1.y);
        acc[3] += p0 * bf_hi(u0.y) + p1 * bf_hi(u1.y);
        acc[4] += p0 * bf_lo(u0.z) + p1 * bf_lo(u1.z);
        acc[5] += p0 * bf_hi(u0.z) + p1 * bf_hi(u1.z);
        acc[6] += p0 * bf_lo(u0.w) + p1 * bf_lo(u1.w);
        acc[7] += p0 * bf_hi(u0.w) + p1 * bf_hi(u1.w);
    }
    if (j < o1){
        int sc = csr[j];
        float p = eex[j * 4 + head] * invh;
        uint4 u = *(const uint4*)&h1[(size_t)sc * 128 + c0];
        acc[0] += p * bf_lo(u.x); acc[1] += p * bf_hi(u.x);
        acc[2] += p * bf_lo(u.y); acc[3] += p * bf_hi(u.y);
        acc[4] += p * bf_lo(u.z); acc[5] += p * bf_hi(u.z);
        acc[6] += p * bf_lo(u.w); acc[7] += p * bf_hi(u.w);
    }
    if (q == 0){
        uint4 u = *(const uint4*)&h1[(size_t)n * 128 + c0];
        acc[0] += ps * bf_lo(u.x); acc[1] += ps * bf_hi(u.x);
        acc[2] += ps * bf_lo(u.y); acc[3] += ps * bf_hi(u.y);
        acc[4] += ps * bf_lo(u.z); acc[5] += ps * bf_hi(u.z);
        acc[6] += ps * bf_lo(u.w); acc[7] += ps * bf_hi(u.w);
    }
    #pragma unroll
    for (int i = 0; i < 8; i++){
        acc[i] += __shfl_xor(acc[i], 16);
        acc[i] += __shfl_xor(acc[i], 32);
    }
    if (q == 0){
        float4 bA = *(const float4*)&b1[c0];
        float4 bB = *(const float4*)&b1[c0 + 4];
        u16 pk[8];
        pk[0] = to_bf16(fmaxf(acc[0] + bA.x, 0.f));
        pk[1] = to_bf16(fmaxf(acc[1] + bA.y, 0.f));
        pk[2] = to_bf16(fmaxf(acc[2] + bA.z, 0.f));
        pk[3] = to_bf16(fmaxf(acc[3] + bA.w, 0.f));
        pk[4] = to_bf16(fmaxf(acc[4] + bB.x, 0.f));
        pk[5] = to_bf16(fmaxf(acc[5] + bB.y, 0.f));
        pk[6] = to_bf16(fmaxf(acc[6] + bB.z, 0.f));
        pk[7] = to_bf16(fmaxf(acc[7] + bB.w, 0.f));
        *(uint4*)&outm[(size_t)n * 128 + c0] = *(uint4*)pk;
    }
}

// ------- layer-2 aggregate -------
__global__ __launch_bounds__(256) void gat_agg2(const int* __restrict__ off,
                                                const u16* __restrict__ csr,
                                                float* __restrict__ eex,
                                                const u16* __restrict__ h2,
                                                const float* __restrict__ als,
                                                const float* __restrict__ ald,
                                                const float* __restrict__ b2,
                                                void* __restrict__ outv, int N,
                                                const int* __restrict__ flag){
    int lane = threadIdx.x & 63;
    int n = blockIdx.x * 4 + (threadIdx.x >> 6);
    if (n >= N) return;
    int o0 = off[n], o1 = off[n + 1];
    float aldn = ald[n];
    float s = 0.f;
    for (int j = o0 + lane; j < o1; j += 64){
        int sc = csr[j];
        float e = eexp(als[sc] + aldn);
        eex[j] = e;
        s += e;
    }
    #pragma unroll
    for (int d = 1; d < 64; d <<= 1) s += __shfl_xor(s, d);
    float esx = eexp(als[n] + aldn);
    float inv = 1.f / (s + esx + 1e-16f);
    float ps = esx * inv;
    __builtin_amdgcn_s_waitcnt(0);
    int oc = lane >> 3, ol = lane & 7;
    int c0 = ol * 8;
    float acc[8] = {};
    int j = o0 + oc;
    for (; j + 8 < o1; j += 16){
        int sc0 = csr[j], sc1 = csr[j + 8];
        float p0 = eex[j] * inv;
        float p1 = eex[j + 8] * inv;
        uint4 u0 = *(const uint4*)&h2[(size_t)sc0 * 64 + c0];
        uint4 u1 = *(const uint4*)&h2[(size_t)sc1 * 64 + c0];
        acc[0] += p0 * bf_lo(u0.x) + p1 * bf_lo(u1.x);
        acc[1] += p0 * bf_hi(u0.x) + p1 * bf_hi(u1.x);
        acc[2] += p0 * bf_lo(u0.y) + p1 * bf_lo(u1.y);
        acc[3] += p0 * bf_hi(u0.y) + p1 * bf_hi(u1.y);
        acc[4] += p0 * bf_lo(u0.z) + p1 * bf_lo(u1.z);
        acc[5] += p0 * bf_hi(u0.z) + p1 * bf_hi(u1.z);
        acc[6] += p0 * bf_lo(u0.w) + p1 * bf_lo(u1.w);
        acc[7] += p0 * bf_hi(u0.w) + p1 * bf_hi(u1.w);
    }
    if (j < o1){
        int sc = csr[j];
        float p = eex[j] * inv;
        uint4 u = *(const uint4*)&h2[(size_t)sc * 64 + c0];
        acc[0] += p * bf_lo(u.x); acc[1] += p * bf_hi(u.x);
        acc[2] += p * bf_lo(u.y); acc[3] += p * bf_hi(u.y);
        acc[4] += p * bf_lo(u.z); acc[5] += p * bf_hi(u.z);
        acc[6] += p * bf_lo(u.w); acc[7] += p * bf_hi(u.w);
    }
    if (oc == 0){
        uint4 u = *(const uint4*)&h2[(size_t)n * 64 + c0];
        acc[0] += ps * bf_lo(u.x); acc[1] += ps * bf_hi(u.x);
        acc[2] += ps * bf_lo(u.y); acc[3] += ps * bf_hi(u.y);
        acc[4] += ps * bf_lo(u.z); acc[5] += ps * bf_hi(u.z);
        acc[6] += ps * bf_lo(u.w); acc[7] += ps * bf_hi(u.w);
    }
    #pragma unroll
    for (int i = 0; i < 8; i++){
        acc[i] += __shfl_xor(acc[i], 8);
        acc[i] += __shfl_xor(acc[i], 16);
        acc[i] += __shfl_xor(acc[i], 32);
    }
    if (oc == 0){
        float4 bA = *(const float4*)&b2[c0];
        float4 bB = *(const float4*)&b2[c0 + 4];
        float r[8];
        r[0] = acc[0] + bA.x; r[1] = acc[1] + bA.y;
        r[2] = acc[2] + bA.z; r[3] = acc[3] + bA.w;
        r[4] = acc[4] + bB.x; r[5] = acc[5] + bB.y;
        r[6] = acc[6] + bB.z; r[7] = acc[7] + bB.w;
        if (*flag){
            u16 pk[8];
            #pragma unroll
            for (int i = 0; i < 8; i++) pk[i] = to_bf16(r[i]);
            *(uint4*)&((u16*)outv)[(size_t)n * 64 + c0] = *(uint4*)pk;
        } else {
            float* op = &((float*)outv)[(size_t)n * 64 + c0];
            *(float4*)op = make_float4(r[0], r[1], r[2], r[3]);
            *(float4*)(op + 4) = make_float4(r[4], r[5], r[6], r[7]);
        }
    }
}

extern "C" void kernel_launch(void* const* d_in, const int* in_sizes, int n_in,
                              void* d_out, int out_size, void* d_ws, size_t ws_size,
                              hipStream_t stream){
    const int* ei  = (const int*)d_in[1];
    const int N = in_sizes[0] / 128;
    const int E = in_sizes[1] / 2;
    const int* src = ei;
    const int* dst = ei + E;
    const int binsz = (N + 7) / 8;

    char* w = (char*)d_ws;
    auto alloc = [&](size_t bytes){ char* p = w; w += (bytes + 255) & ~(size_t)255; return p; };
    int*   flag = (int*)  alloc(4);
    int*   deg  = (int*)  alloc((size_t)N * 4);
    int*   off  = (int*)  alloc((size_t)(N + 1) * 4);
    int*   cur  = (int*)  alloc((size_t)N * 4);
    int*   bsum = (int*)  alloc(64 * 4);
    u16*   csr  = (u16*)  alloc((size_t)E * 2);
    float* eex1 = (float*)alloc((size_t)E * 4 * 4);
    u16*   W1t  = (u16*)  alloc(128 * 128 * 2);
    u16*   W2t  = (u16*)  alloc(64 * 128 * 2);
    float* as1f = (float*)alloc(128 * 4);
    float* ad1f = (float*)alloc(128 * 4);
    float* b1f  = (float*)alloc(128 * 4);
    float* as2f = (float*)alloc(64 * 4);
    float* ad2f = (float*)alloc(64 * 4);
    float* b2f  = (float*)alloc(64 * 4);
    u16*   Xb   = (u16*)  alloc((size_t)N * 128 * 2);
    u16*   h1b  = (u16*)  alloc((size_t)N * 128 * 2);
    u16*   hmidb= (u16*)  alloc((size_t)N * 128 * 2);
    u16*   h2b  = (u16*)  alloc((size_t)N * 64 * 2);
    float* als1 = (float*)alloc((size_t)N * 4 * 4);
    float* ald1 = (float*)alloc((size_t)N * 4 * 4);
    float* eex2 = eex1;
    float* als2 = als1;
    float* ald2 = ald1;

    hipMemsetAsync(deg, 0, (size_t)N * 4, stream);

    Mega1Args m1;
    m1.dst = dst; m1.src = src; m1.deg = deg; m1.E = E; m1.binsz = binsz;
    m1.xin = d_in[0]; m1.Xb = Xb; m1.nx = N * 128;
    m1.W1 = d_in[2]; m1.W2 = d_in[6]; m1.W1t = W1t; m1.W2t = W2t;
    const void* vin[6]  = {d_in[3], d_in[4], d_in[5], d_in[7], d_in[8], d_in[9]};
    float* vout[6] = {as1f, ad1f, b1f, as2f, ad2f, b2f};
    for (int s = 0; s < 6; s++){ m1.vin[s] = vin[s]; m1.vout[s] = vout[s]; }
    m1.flag = flag;
    int cvt_total = N * 128 + 128 * 128 + 64 * 128 + 576;
    int m1_blocks = CB + (cvt_total + 255) / 256;
    mega1<<<m1_blocks, 256, 0, stream>>>(m1);

    const int B = (N + SCHUNK - 1) / SCHUNK;
    scan_part<<<B, 256, 0, stream>>>(deg, bsum, N);
    scan_tops<<<1, 64, 0, stream>>>(bsum, B);
    scan_final<<<B, 256, 0, stream>>>(deg, bsum, off, cur, N);

    Mega2Args m2;
    m2.dst = dst; m2.src = src; m2.cur = cur; m2.csr = csr; m2.E = E; m2.binsz = binsz;
    m2.Xb = Xb; m2.W1t = W1t; m2.HB = h1b;
    m2.a_s = as1f; m2.a_d = ad1f; m2.al_s = als1; m2.al_d = ald1;
    m2.N = N;
    int m2_blocks = SB + (N + 63) / 64;
    mega2<<<m2_blocks, 256, 0, stream>>>(m2);

    gat_agg1<<<(N + 3) / 4, 256, 0, stream>>>(off, csr, eex1, h1b, als1, ald1, b1f, hmidb, N);

    gemm2_logits<<<(N + 63) / 64, 256, 0, stream>>>(hmidb, W2t, h2b, as2f, ad2f, als2, ald2, N);

    gat_agg2<<<(N + 3) / 4, 256, 0, stream>>>(off, csr, eex2, h2b, als2, ald2, b2f, d_out, N, flag);
}

// Round 13
// 276.904 us; speedup vs baseline: 1.4760x; 1.0914x over previous
//
#include <hip/hip_runtime.h>

typedef unsigned short u16;
typedef unsigned int u32;
typedef __attribute__((ext_vector_type(8))) short bf16x8;
typedef __attribute__((ext_vector_type(4))) float f32x4;

__device__ __forceinline__ float bf(u16 u){ return __uint_as_float(((u32)u) << 16); }
__device__ __forceinline__ float bf_lo(u32 u){ return __uint_as_float(u << 16); }
__device__ __forceinline__ float bf_hi(u32 u){ return __uint_as_float(u & 0xFFFF0000u); }
__device__ __forceinline__ u16 to_bf16(float f){
    u32 x = __float_as_uint(f);
    u32 r = (x + 0x7FFFu + ((x >> 16) & 1u)) >> 16;
    return (u16)r;
}
__device__ __forceinline__ float leaky(float v){ return (v >= 0.f) ? v : 0.2f * v; }
__device__ __forceinline__ float eexp(float v){
    return __expf(fminf(leaky(v), 80.f));
}
__device__ __forceinline__ float ldany(const void* p, int i, int fl){
    return fl ? bf(((const u16*)p)[i]) : ((const float*)p)[i];
}
__device__ __forceinline__ u16 ldany_bf(const void* p, int i, int fl){
    return fl ? ((const u16*)p)[i] : to_bf16(((const float*)p)[i]);
}

constexpr int NS = 256;      // edge slices (histogram/scatter blocks)
// bins: 512 dst nodes per bin (shift 9); NBIN = ceil(N/512) <= 128 for N <= 65536

// ========== k1: per-slice LDS histogram (no global atomics) + input conversion ==========
struct HistCvtArgs {
    const int* dst; const int* src; int E; int chE; u16* cnt; int NBIN;
    const void* xin; u16* Xb; int nx;
    const void* W1; const void* W2; u16* W1t; u16* W2t;
    const void* vin[6]; float* vout[6];
    int* flag;
};
__global__ __launch_bounds__(256) void hist_cvt(HistCvtArgs a){
    int b = blockIdx.x;
    if (b < NS){
        __shared__ u32 hist[128];
        if (threadIdx.x < 128) hist[threadIdx.x] = 0;
        __syncthreads();
        int s0 = b * a.chE, s1 = min(a.E, s0 + a.chE);
        for (int i = s0 + threadIdx.x; i < s1; i += 256){
            int d = a.dst[i];
            if (a.src[i] != d) atomicAdd(&hist[d >> 9], 1);
        }
        __syncthreads();
        if (threadIdx.x < a.NBIN)
            a.cnt[b * a.NBIN + threadIdx.x] = (u16)hist[threadIdx.x];
        return;
    }
    __shared__ int sflag;
    const u16* x16 = (const u16*)a.xin;
    if (threadIdx.x < 64){
        int ok = 1;
        for (int i = threadIdx.x; i < 256; i += 64){
            u16 v = x16[i];
            int e = (v >> 7) & 0xFF;
            if (!((e >= 100 && e <= 140) || (v & 0x7FFFu) == 0)) ok = 0;
        }
        unsigned long long bl = __ballot(ok);
        if (threadIdx.x == 0) sflag = (__popcll(bl) >= 62) ? 1 : 0;
    }
    __syncthreads();
    int fl = sflag;
    int ci = (b - NS) * 256 + threadIdx.x;
    if (ci == 0) *a.flag = fl;
    if (ci < a.nx){ a.Xb[ci] = ldany_bf(a.xin, ci, fl); return; }
    ci -= a.nx;
    if (ci < 128 * 128){
        int n = ci >> 7, k = ci & 127;
        a.W1t[ci] = ldany_bf(a.W1, k * 128 + n, fl);
        return;
    }
    ci -= 128 * 128;
    if (ci < 64 * 128){
        int n = ci >> 7, k = ci & 127;
        a.W2t[ci] = ldany_bf(a.W2, k * 64 + n, fl);
        return;
    }
    ci -= 64 * 128;
    const int vsz[6] = {128, 128, 128, 64, 64, 64};
    #pragma unroll
    for (int s = 0; s < 6; s++){
        if (ci < vsz[s]){ a.vout[s][ci] = ldany(a.vin[s], ci, fl); return; }
        ci -= vsz[s];
    }
}

// ========== k2: scan counts in bin-major order -> S[b*NS+g] (global bucket bases) ==========
__global__ __launch_bounds__(1024) void scan_cnt(const u16* __restrict__ cnt,
                                                 u32* __restrict__ S, int NBIN){
    __shared__ int wsum[16];
    int t = threadIdx.x;
    int M = NBIN * NS;
    int C = (M + 1023) / 1024;
    int f0 = t * C;
    int s = 0;
    for (int i = 0; i < C; i++){
        int f = f0 + i;
        if (f < M) s += cnt[(f & 255) * NBIN + (f >> 8)];   // bin-major f -> g-major storage
    }
    int v = s;
    #pragma unroll
    for (int d = 1; d < 64; d <<= 1){
        int o = __shfl_up(v, d);
        if ((t & 63) >= d) v += o;
    }
    if ((t & 63) == 63) wsum[t >> 6] = v;
    __syncthreads();
    int woff = 0;
    for (int wv = 0; wv < (t >> 6); wv++) woff += wsum[wv];
    int run = woff + v - s;
    for (int i = 0; i < C; i++){
        int f = f0 + i;
        if (f < M){
            S[f] = run;
            run += cnt[(f & 255) * NBIN + (f >> 8)];
        }
    }
    if (t == 1023) S[M] = run;
}

// ==== k3: per-slice bucket scatter (LDS-atomic slot alloc) + MFMA GEMM1 + fused logits ====
struct BucketGemmArgs {
    const int* dst; const int* src; int E; int chE; const u32* S; int NBIN;
    u32* bucket;
    const u16* Xb; const u16* W1t; u16* HB;
    const float* a_s; const float* a_d; float* al_s; float* al_d;
    int N;
};
__global__ __launch_bounds__(256) void bucket_gemm(BucketGemmArgs a){
    int b = blockIdx.x;
    if (b < NS){
        __shared__ u32 cur[128];
        if (threadIdx.x < a.NBIN) cur[threadIdx.x] = a.S[threadIdx.x * NS + b];
        __syncthreads();
        int s0 = b * a.chE, s1 = min(a.E, s0 + a.chE);
        for (int i = s0 + threadIdx.x; i < s1; i += 256){
            int d = a.dst[i];
            int s = a.src[i];
            if (s != d){
                u32 pos = atomicAdd(&cur[d >> 9], 1);
                a.bucket[pos] = ((u32)d << 16) | (u32)s;
            }
        }
        return;
    }
    int gb = b - NS;
    int lane = threadIdx.x & 63;
    int w = threadIdx.x >> 6;
    int row0 = gb * 64 + w * 16;
    int m = lane & 15, quad = lane >> 4;
    int arow = row0 + m;
    if (arow >= a.N) arow = a.N - 1;
    f32x4 acc[8];
    #pragma unroll
    for (int j = 0; j < 8; j++) acc[j] = (f32x4){0.f, 0.f, 0.f, 0.f};
    const u16* ap = a.Xb + (size_t)arow * 128 + quad * 8;
    const u16* bp = a.W1t + (size_t)m * 128 + quad * 8;
    #pragma unroll
    for (int kc = 0; kc < 4; kc++){
        bf16x8 av = *(const bf16x8*)(ap + kc * 32);
        #pragma unroll
        for (int nb = 0; nb < 8; nb++){
            bf16x8 bv = *(const bf16x8*)(bp + nb * 16 * 128 + kc * 32);
            acc[nb] = __builtin_amdgcn_mfma_f32_16x16x32_bf16(av, bv, acc[nb], 0, 0, 0);
        }
    }
    #pragma unroll
    for (int nb = 0; nb < 8; nb++){
        #pragma unroll
        for (int r = 0; r < 4; r++){
            int grow = row0 + quad * 4 + r;
            if (grow < a.N) a.HB[(size_t)grow * 128 + nb * 16 + m] = to_bf16(acc[nb][r]);
        }
    }
    float asr[8], adr[8];
    #pragma unroll
    for (int nb = 0; nb < 8; nb++){ asr[nb] = a.a_s[nb * 16 + m]; adr[nb] = a.a_d[nb * 16 + m]; }
    #pragma unroll
    for (int r = 0; r < 4; r++){
        int grow = row0 + quad * 4 + r;
        #pragma unroll
        for (int h = 0; h < 4; h++){
            float ps = acc[2 * h][r] * asr[2 * h] + acc[2 * h + 1][r] * asr[2 * h + 1];
            float pd = acc[2 * h][r] * adr[2 * h] + acc[2 * h + 1][r] * adr[2 * h + 1];
            #pragma unroll
            for (int d = 1; d < 16; d <<= 1){
                ps += __shfl_xor(ps, d);
                pd += __shfl_xor(pd, d);
            }
            if (m == h && grow < a.N){
                a.al_s[grow * 4 + h] = ps;
                a.al_d[grow * 4 + h] = pd;
            }
        }
    }
}

// ==== k4: per-bin CSR finalize — LDS degree count + scan, coalesced off, L2-local csr ====
__global__ __launch_bounds__(256) void bin_csr(const u32* __restrict__ S,
                                               const u32* __restrict__ bucket,
                                               int* __restrict__ off,
                                               u16* __restrict__ csr,
                                               int N, int NBIN){
    __shared__ u32 degL[512];
    __shared__ u32 curL[512];
    __shared__ int wsum[4];
    int b = blockIdx.x, t = threadIdx.x;
    int lo = b << 9;
    u32 base = S[b * NS];
    u32 end  = S[(b + 1) * NS];     // b == NBIN-1 reads S[M] = total
    degL[t] = 0; degL[t + 256] = 0;
    __syncthreads();
    for (u32 i = base + t; i < end; i += 256){
        u32 pr = bucket[i];
        atomicAdd(&degL[(pr >> 16) - lo], 1);
    }
    __syncthreads();
    u32 d0 = degL[2 * t], d1 = degL[2 * t + 1];
    int p = (int)(d0 + d1);
    int v = p;
    #pragma unroll
    for (int d = 1; d < 64; d <<= 1){
        int o = __shfl_up(v, d);
        if ((t & 63) >= d) v += o;
    }
    if ((t & 63) == 63) wsum[t >> 6] = v;
    __syncthreads();
    int woff = 0;
    for (int wv = 0; wv < (t >> 6); wv++) woff += wsum[wv];
    int eb = woff + v - p;
    curL[2 * t] = eb;
    curL[2 * t + 1] = eb + d0;
    int n0 = lo + 2 * t, n1 = lo + 2 * t + 1;
    if (n0 < N) off[n0] = (int)(base + eb);
    if (n1 < N) off[n1] = (int)(base + eb + d0);
    if (b == NBIN - 1 && t == 255) off[N] = (int)end;
    __syncthreads();
    for (u32 i = base + t; i < end; i += 256){
        u32 pr = bucket[i];
        u32 pos = base + atomicAdd(&curL[(pr >> 16) - lo], 1);
        csr[pos] = (u16)(pr & 0xFFFF);
    }
}

// ============ GEMM2 (64 cols) with fused logits (H=1) ============
__global__ __launch_bounds__(256) void gemm2_logits(const u16* __restrict__ Xb,
                                                    const u16* __restrict__ Wt,
                                                    u16* __restrict__ HB,
                                                    const float* __restrict__ a_s,
                                                    const float* __restrict__ a_d,
                                                    float* __restrict__ al_s,
                                                    float* __restrict__ al_d, int N){
    int lane = threadIdx.x & 63;
    int w = threadIdx.x >> 6;
    int row0 = blockIdx.x * 64 + w * 16;
    int m = lane & 15, quad = lane >> 4;
    int arow = row0 + m;
    if (arow >= N) arow = N - 1;
    f32x4 acc[4];
    #pragma unroll
    for (int j = 0; j < 4; j++) acc[j] = (f32x4){0.f, 0.f, 0.f, 0.f};
    const u16* ap = Xb + (size_t)arow * 128 + quad * 8;
    const u16* bp = Wt + (size_t)m * 128 + quad * 8;
    #pragma unroll
    for (int kc = 0; kc < 4; kc++){
        bf16x8 av = *(const bf16x8*)(ap + kc * 32);
        #pragma unroll
        for (int nb = 0; nb < 4; nb++){
            bf16x8 bv = *(const bf16x8*)(bp + nb * 16 * 128 + kc * 32);
            acc[nb] = __builtin_amdgcn_mfma_f32_16x16x32_bf16(av, bv, acc[nb], 0, 0, 0);
        }
    }
    #pragma unroll
    for (int nb = 0; nb < 4; nb++){
        #pragma unroll
        for (int r = 0; r < 4; r++){
            int grow = row0 + quad * 4 + r;
            if (grow < N) HB[(size_t)grow * 64 + nb * 16 + m] = to_bf16(acc[nb][r]);
        }
    }
    float asr[4], adr[4];
    #pragma unroll
    for (int nb = 0; nb < 4; nb++){ asr[nb] = a_s[nb * 16 + m]; adr[nb] = a_d[nb * 16 + m]; }
    #pragma unroll
    for (int r = 0; r < 4; r++){
        int grow = row0 + quad * 4 + r;
        float ps = 0.f, pd = 0.f;
        #pragma unroll
        for (int nb = 0; nb < 4; nb++){ ps += acc[nb][r] * asr[nb]; pd += acc[nb][r] * adr[nb]; }
        #pragma unroll
        for (int d = 1; d < 16; d <<= 1){
            ps += __shfl_xor(ps, d);
            pd += __shfl_xor(pd, d);
        }
        if (m == 0 && grow < N){
            al_s[grow] = ps;
            al_d[grow] = pd;
        }
    }
}

// ------- layer-1 aggregate -------
__global__ __launch_bounds__(256) void gat_agg1(const int* __restrict__ off,
                                                const u16* __restrict__ csr,
                                                float* __restrict__ eex,
                                                const u16* __restrict__ h1,
                                                const float* __restrict__ als,
                                                const float* __restrict__ ald,
                                                const float* __restrict__ b1,
                                                u16* __restrict__ outm, int N){
    int lane = threadIdx.x & 63;
    int n = blockIdx.x * 4 + (threadIdx.x >> 6);
    if (n >= N) return;
    int o0 = off[n], o1 = off[n + 1];
    int h = lane & 3;
    float aldh = ald[n * 4 + h];
    float s = 0.f;
    for (int j = o0 + (lane >> 2); j < o1; j += 16){
        int sc = csr[j];
        float e = eexp(als[sc * 4 + h] + aldh);
        eex[j * 4 + h] = e;
        s += e;
    }
    #pragma unroll
    for (int d = 4; d < 64; d <<= 1) s += __shfl_xor(s, d);
    float esx = eexp(als[n * 4 + h] + aldh);
    float inv = 1.f / (s + esx + 1e-16f);
    float psv = esx * inv;
    __builtin_amdgcn_s_waitcnt(0);
    int q = lane >> 4, ql = lane & 15;
    int c0 = ql * 8;
    int head = ql >> 2;
    float invh = __shfl(inv, head);
    float ps   = __shfl(psv, head);
    float acc[8] = {};
    int j = o0 + q;
    for (; j + 4 < o1; j += 8){
        int sc0 = csr[j], sc1 = csr[j + 4];
        float p0 = eex[j * 4 + head] * invh;
        float p1 = eex[(j + 4) * 4 + head] * invh;
        uint4 u0 = *(const uint4*)&h1[(size_t)sc0 * 128 + c0];
        uint4 u1 = *(const uint4*)&h1[(size_t)sc1 * 128 + c0];
        acc[0] += p0 * bf_lo(u0.x) + p1 * bf_lo(u1.x);
        acc[1] += p0 * bf_hi(u0.x) + p1 * bf_hi(u1.x);
        acc[2] += p0 * bf_lo(u0.y) + p1 * bf_lo(u1.y);
        acc[3] += p0 * bf_hi(u0.y) + p1 * bf_hi(u1.y);
        acc[4] += p0 * bf_lo(u0.z) + p1 * bf_lo(u1.z);
        acc[5] += p0 * bf_hi(u0.z) + p1 * bf_hi(u1.z);
        acc[6] += p0 * bf_lo(u0.w) + p1 * bf_lo(u1.w);
        acc[7] += p0 * bf_hi(u0.w) + p1 * bf_hi(u1.w);
    }
    if (j < o1){
        int sc = csr[j];
        float p = eex[j * 4 + head] * invh;
        uint4 u = *(const uint4*)&h1[(size_t)sc * 128 + c0];
        acc[0] += p * bf_lo(u.x); acc[1] += p * bf_hi(u.x);
        acc[2] += p * bf_lo(u.y); acc[3] += p * bf_hi(u.y);
        acc[4] += p * bf_lo(u.z); acc[5] += p * bf_hi(u.z);
        acc[6] += p * bf_lo(u.w); acc[7] += p * bf_hi(u.w);
    }
    if (q == 0){
        uint4 u = *(const uint4*)&h1[(size_t)n * 128 + c0];
        acc[0] += ps * bf_lo(u.x); acc[1] += ps * bf_hi(u.x);
        acc[2] += ps * bf_lo(u.y); acc[3] += ps * bf_hi(u.y);
        acc[4] += ps * bf_lo(u.z); acc[5] += ps * bf_hi(u.z);
        acc[6] += ps * bf_lo(u.w); acc[7] += ps * bf_hi(u.w);
    }
    #pragma unroll
    for (int i = 0; i < 8; i++){
        acc[i] += __shfl_xor(acc[i], 16);
        acc[i] += __shfl_xor(acc[i], 32);
    }
    if (q == 0){
        float4 bA = *(const float4*)&b1[c0];
        float4 bB = *(const float4*)&b1[c0 + 4];
        u16 pk[8];
        pk[0] = to_bf16(fmaxf(acc[0] + bA.x, 0.f));
        pk[1] = to_bf16(fmaxf(acc[1] + bA.y, 0.f));
        pk[2] = to_bf16(fmaxf(acc[2] + bA.z, 0.f));
        pk[3] = to_bf16(fmaxf(acc[3] + bA.w, 0.f));
        pk[4] = to_bf16(fmaxf(acc[4] + bB.x, 0.f));
        pk[5] = to_bf16(fmaxf(acc[5] + bB.y, 0.f));
        pk[6] = to_bf16(fmaxf(acc[6] + bB.z, 0.f));
        pk[7] = to_bf16(fmaxf(acc[7] + bB.w, 0.f));
        *(uint4*)&outm[(size_t)n * 128 + c0] = *(uint4*)pk;
    }
}

// ------- layer-2 aggregate -------
__global__ __launch_bounds__(256) void gat_agg2(const int* __restrict__ off,
                                                const u16* __restrict__ csr,
                                                float* __restrict__ eex,
                                                const u16* __restrict__ h2,
                                                const float* __restrict__ als,
                                                const float* __restrict__ ald,
                                                const float* __restrict__ b2,
                                                void* __restrict__ outv, int N,
                                                const int* __restrict__ flag){
    int lane = threadIdx.x & 63;
    int n = blockIdx.x * 4 + (threadIdx.x >> 6);
    if (n >= N) return;
    int o0 = off[n], o1 = off[n + 1];
    float aldn = ald[n];
    float s = 0.f;
    for (int j = o0 + lane; j < o1; j += 64){
        int sc = csr[j];
        float e = eexp(als[sc] + aldn);
        eex[j] = e;
        s += e;
    }
    #pragma unroll
    for (int d = 1; d < 64; d <<= 1) s += __shfl_xor(s, d);
    float esx = eexp(als[n] + aldn);
    float inv = 1.f / (s + esx + 1e-16f);
    float ps = esx * inv;
    __builtin_amdgcn_s_waitcnt(0);
    int oc = lane >> 3, ol = lane & 7;
    int c0 = ol * 8;
    float acc[8] = {};
    int j = o0 + oc;
    for (; j + 8 < o1; j += 16){
        int sc0 = csr[j], sc1 = csr[j + 8];
        float p0 = eex[j] * inv;
        float p1 = eex[j + 8] * inv;
        uint4 u0 = *(const uint4*)&h2[(size_t)sc0 * 64 + c0];
        uint4 u1 = *(const uint4*)&h2[(size_t)sc1 * 64 + c0];
        acc[0] += p0 * bf_lo(u0.x) + p1 * bf_lo(u1.x);
        acc[1] += p0 * bf_hi(u0.x) + p1 * bf_hi(u1.x);
        acc[2] += p0 * bf_lo(u0.y) + p1 * bf_lo(u1.y);
        acc[3] += p0 * bf_hi(u0.y) + p1 * bf_hi(u1.y);
        acc[4] += p0 * bf_lo(u0.z) + p1 * bf_lo(u1.z);
        acc[5] += p0 * bf_hi(u0.z) + p1 * bf_hi(u1.z);
        acc[6] += p0 * bf_lo(u0.w) + p1 * bf_lo(u1.w);
        acc[7] += p0 * bf_hi(u0.w) + p1 * bf_hi(u1.w);
    }
    if (j < o1){
        int sc = csr[j];
        float p = eex[j] * inv;
        uint4 u = *(const uint4*)&h2[(size_t)sc * 64 + c0];
        acc[0] += p * bf_lo(u.x); acc[1] += p * bf_hi(u.x);
        acc[2] += p * bf_lo(u.y); acc[3] += p * bf_hi(u.y);
        acc[4] += p * bf_lo(u.z); acc[5] += p * bf_hi(u.z);
        acc[6] += p * bf_lo(u.w); acc[7] += p * bf_hi(u.w);
    }
    if (oc == 0){
        uint4 u = *(const uint4*)&h2[(size_t)n * 64 + c0];
        acc[0] += ps * bf_lo(u.x); acc[1] += ps * bf_hi(u.x);
        acc[2] += ps * bf_lo(u.y); acc[3] += ps * bf_hi(u.y);
        acc[4] += ps * bf_lo(u.z); acc[5] += ps * bf_hi(u.z);
        acc[6] += ps * bf_lo(u.w); acc[7] += ps * bf_hi(u.w);
    }
    #pragma unroll
    for (int i = 0; i < 8; i++){
        acc[i] += __shfl_xor(acc[i], 8);
        acc[i] += __shfl_xor(acc[i], 16);
        acc[i] += __shfl_xor(acc[i], 32);
    }
    if (oc == 0){
        float4 bA = *(const float4*)&b2[c0];
        float4 bB = *(const float4*)&b2[c0 + 4];
        float r[8];
        r[0] = acc[0] + bA.x; r[1] = acc[1] + bA.y;
        r[2] = acc[2] + bA.z; r[3] = acc[3] + bA.w;
        r[4] = acc[4] + bB.x; r[5] = acc[5] + bB.y;
        r[6] = acc[6] + bB.z; r[7] = acc[7] + bB.w;
        if (*flag){
            u16 pk[8];
            #pragma unroll
            for (int i = 0; i < 8; i++) pk[i] = to_bf16(r[i]);
            *(uint4*)&((u16*)outv)[(size_t)n * 64 + c0] = *(uint4*)pk;
        } else {
            float* op = &((float*)outv)[(size_t)n * 64 + c0];
            *(float4*)op = make_float4(r[0], r[1], r[2], r[3]);
            *(float4*)(op + 4) = make_float4(r[4], r[5], r[6], r[7]);
        }
    }
}

extern "C" void kernel_launch(void* const* d_in, const int* in_sizes, int n_in,
                              void* d_out, int out_size, void* d_ws, size_t ws_size,
                              hipStream_t stream){
    const int* ei  = (const int*)d_in[1];
    const int N = in_sizes[0] / 128;
    const int E = in_sizes[1] / 2;
    const int* src = ei;
    const int* dst = ei + E;
    const int NBIN = (N + 511) >> 9;         // <=128 while N<=65536
    const int chE  = (E + NS - 1) / NS;

    char* w = (char*)d_ws;
    auto alloc = [&](size_t bytes){ char* p = w; w += (bytes + 255) & ~(size_t)255; return p; };
    int*   flag  = (int*)  alloc(4);
    u16*   cnt   = (u16*)  alloc((size_t)NS * NBIN * 2);
    u32*   S     = (u32*)  alloc(((size_t)NS * NBIN + 1) * 4);
    u32*   bucket= (u32*)  alloc((size_t)E * 4);
    int*   off   = (int*)  alloc((size_t)(N + 1) * 4);
    u16*   csr   = (u16*)  alloc((size_t)E * 2);
    float* eex1  = (float*)alloc((size_t)E * 4 * 4);
    u16*   W1t   = (u16*)  alloc(128 * 128 * 2);
    u16*   W2t   = (u16*)  alloc(64 * 128 * 2);
    float* as1f  = (float*)alloc(128 * 4);
    float* ad1f  = (float*)alloc(128 * 4);
    float* b1f   = (float*)alloc(128 * 4);
    float* as2f  = (float*)alloc(64 * 4);
    float* ad2f  = (float*)alloc(64 * 4);
    float* b2f   = (float*)alloc(64 * 4);
    u16*   Xb    = (u16*)  alloc((size_t)N * 128 * 2);
    u16*   h1b   = (u16*)  alloc((size_t)N * 128 * 2);
    u16*   hmidb = (u16*)  alloc((size_t)N * 128 * 2);
    u16*   h2b   = (u16*)  alloc((size_t)N * 64 * 2);
    float* als1  = (float*)alloc((size_t)N * 4 * 4);
    float* ald1  = (float*)alloc((size_t)N * 4 * 4);
    float* eex2  = eex1;
    float* als2  = als1;
    float* ald2  = ald1;

    HistCvtArgs k1;
    k1.dst = dst; k1.src = src; k1.E = E; k1.chE = chE; k1.cnt = cnt; k1.NBIN = NBIN;
    k1.xin = d_in[0]; k1.Xb = Xb; k1.nx = N * 128;
    k1.W1 = d_in[2]; k1.W2 = d_in[6]; k1.W1t = W1t; k1.W2t = W2t;
    const void* vin[6]  = {d_in[3], d_in[4], d_in[5], d_in[7], d_in[8], d_in[9]};
    float* vout[6] = {as1f, ad1f, b1f, as2f, ad2f, b2f};
    for (int s = 0; s < 6; s++){ k1.vin[s] = vin[s]; k1.vout[s] = vout[s]; }
    k1.flag = flag;
    int cvt_total = N * 128 + 128 * 128 + 64 * 128 + 576;
    hist_cvt<<<NS + (cvt_total + 255) / 256, 256, 0, stream>>>(k1);

    scan_cnt<<<1, 1024, 0, stream>>>(cnt, S, NBIN);

    BucketGemmArgs k3;
    k3.dst = dst; k3.src = src; k3.E = E; k3.chE = chE; k3.S = S; k3.NBIN = NBIN;
    k3.bucket = bucket;
    k3.Xb = Xb; k3.W1t = W1t; k3.HB = h1b;
    k3.a_s = as1f; k3.a_d = ad1f; k3.al_s = als1; k3.al_d = ald1;
    k3.N = N;
    bucket_gemm<<<NS + (N + 63) / 64, 256, 0, stream>>>(k3);

    bin_csr<<<NBIN, 256, 0, stream>>>(S, bucket, off, csr, N, NBIN);

    gat_agg1<<<(N + 3) / 4, 256, 0, stream>>>(off, csr, eex1, h1b, als1, ald1, b1f, hmidb, N);

    gemm2_logits<<<(N + 63) / 64, 256, 0, stream>>>(hmidb, W2t, h2b, as2f, ad2f, als2, ald2, N);

    gat_agg2<<<(N + 3) / 4, 256, 0, stream>>>(off, csr, eex2, h2b, als2, ald2, b2f, d_out, N, flag);
}